// Round 2
// baseline (284.569 us; speedup 1.0000x reference)
//
#include <hip/hip_runtime.h>
#include <hip/hip_bf16.h>
#include <math.h>

#define N_NODES 3072
#define DIM     256
#define NH      8
#define HD      32
#define E_EDGES 98304
#define B_GRAPHS 16
#define MAXC    388     // padded score stride; 388 % 32 == 4
#define TR      16      // rows per attention tile
#define SCALE   0.17677669529663689f   // 1/sqrt(32)

// ---------------- setup: zero counters + graph ranges ----------------
__global__ void setup_misc(const int* __restrict__ batch, int* __restrict__ counts,
                           int* __restrict__ gstart) {
    int i = blockIdx.x * blockDim.x + threadIdx.x;
    if (i < 2 * N_NODES) counts[i] = 0;
    if (i < N_NODES) {
        int b  = batch[i];
        int bp = (i == 0) ? -1 : batch[i - 1];
        for (int g = bp + 1; g <= b; ++g) gstart[g] = i;
        if (i == N_NODES - 1)
            for (int g = b + 1; g <= B_GRAPHS; ++g) gstart[g] = N_NODES;
    }
}

// ---------------- fused QKV projection ----------------
// grid 384, block 256: thread = output column, 8 rows/block.
// x-row loads are wave-uniform -> scalar (SGPR) loads; weight loads coalesced.
__global__ __launch_bounds__(256) void qkv_proj(
    const float* __restrict__ x,
    const float* __restrict__ Wq, const float* __restrict__ bq,
    const float* __restrict__ Wk, const float* __restrict__ bk,
    const float* __restrict__ Wv, const float* __restrict__ bv,
    float* __restrict__ Q, float* __restrict__ K, float* __restrict__ V)
{
    const int row0 = blockIdx.x * 8;
    const int col  = threadIdx.x;
    float accQ[8] = {0,0,0,0,0,0,0,0};
    float accK[8] = {0,0,0,0,0,0,0,0};
    float accV[8] = {0,0,0,0,0,0,0,0};
    const float4* xr = (const float4*)(x + (size_t)row0 * DIM);

    for (int k4 = 0; k4 < DIM / 4; ++k4) {
        float4 xv[8];
        #pragma unroll
        for (int r = 0; r < 8; ++r) xv[r] = xr[(size_t)r * (DIM / 4) + k4];
        const int kb = k4 * 4;
        #define QKV_STEP(COMP, KK) { \
            float wq = Wq[(size_t)(kb + KK) * DIM + col]; \
            float wk = Wk[(size_t)(kb + KK) * DIM + col]; \
            float wv = Wv[(size_t)(kb + KK) * DIM + col]; \
            _Pragma("unroll") \
            for (int r = 0; r < 8; ++r) { \
                float xc = xv[r].COMP; \
                accQ[r] = fmaf(xc, wq, accQ[r]); \
                accK[r] = fmaf(xc, wk, accK[r]); \
                accV[r] = fmaf(xc, wv, accV[r]); } }
        QKV_STEP(x, 0) QKV_STEP(y, 1) QKV_STEP(z, 2) QKV_STEP(w, 3)
        #undef QKV_STEP
    }
    float bqv = bq[col], bkv = bk[col], bvv = bv[col];
    #pragma unroll
    for (int r = 0; r < 8; ++r) {
        size_t o = (size_t)(row0 + r) * DIM + col;
        Q[o] = accQ[r] + bqv;
        K[o] = accK[r] + bkv;
        V[o] = accV[r] + bvv;
    }
}

// ---------------- edge CSR build ----------------
__global__ void edge_count(const int* __restrict__ erow, int* __restrict__ counts) {
    int e = blockIdx.x * blockDim.x + threadIdx.x;
    if (e < E_EDGES) atomicAdd(&counts[erow[e]], 1);
}

__global__ __launch_bounds__(1024) void scan_rows(const int* __restrict__ counts,
                                                  int* __restrict__ rowstart) {
    __shared__ int lds[1024];
    const int t = threadIdx.x;
    int c0 = counts[3 * t], c1 = counts[3 * t + 1], c2 = counts[3 * t + 2];
    int local = c0 + c1 + c2;
    lds[t] = local;
    __syncthreads();
    for (int off = 1; off < 1024; off <<= 1) {
        int v = (t >= off) ? lds[t - off] : 0;
        __syncthreads();
        lds[t] += v;
        __syncthreads();
    }
    int incl = lds[t];
    int base = incl - local;
    rowstart[3 * t]     = base;
    rowstart[3 * t + 1] = base + c0;
    rowstart[3 * t + 2] = base + c0 + c1;
    if (t == 1023) rowstart[N_NODES] = incl;
}

__global__ void edge_fill(const int* __restrict__ erow, const int* __restrict__ ecolin,
                          const float* __restrict__ ea, const float* __restrict__ We,
                          const float* __restrict__ be,
                          const int* __restrict__ rowstart, int* __restrict__ cursor,
                          int* __restrict__ ecol, float* __restrict__ ebias) {
    int e = blockIdx.x * blockDim.x + threadIdx.x;
    if (e >= E_EDGES) return;
    int row = erow[e];
    int pos = rowstart[row] + atomicAdd(&cursor[row], 1);
    ecol[pos] = ecolin[e];
    float a0 = ea[e * 4 + 0], a1 = ea[e * 4 + 1], a2 = ea[e * 4 + 2], a3 = ea[e * 4 + 3];
    #pragma unroll
    for (int h = 0; h < NH; ++h) {
        float b = fmaf(a0, We[0 * NH + h],
                  fmaf(a1, We[1 * NH + h],
                  fmaf(a2, We[2 * NH + h],
                  fmaf(a3, We[3 * NH + h], be[h]))));
        ebias[(size_t)h * E_EDGES + pos] = b;   // [h][E] -> coalesced reads in attn
    }
}

// ---------------- fused block-diagonal attention ----------------
// grid (16 graphs, 24 tiles, 8 heads), block 256, TR=16 rows/tile
__global__ __launch_bounds__(256) void attn(
    const float* __restrict__ Q, const float* __restrict__ K, const float* __restrict__ V,
    const int* __restrict__ gstart, const int* __restrict__ rowstart,
    const int* __restrict__ ecol, const float* __restrict__ ebias,
    float* __restrict__ pre)
{
    __shared__ float s[TR][MAXC];
    __shared__ float rowinv[TR];
    __shared__ int   rs_sh[TR + 1];

    const int g = blockIdx.x, tile = blockIdx.y, h = blockIdx.z;
    const int gs = gstart[g], ge = gstart[g + 1];
    const int row0 = gs + tile * TR;
    if (row0 >= ge) return;
    const int nrows = min(TR, ge - row0);
    const int ncols = ge - gs;
    const int t = threadIdx.x;

    if (t <= nrows) rs_sh[t] = rowstart[row0 + t];

    // ---- QK^T: thread = column; K in VGPRs, Q rows via wave-uniform (scalar) loads
    if (t < ncols) {
        const float4* kp = (const float4*)(K + (size_t)(gs + t) * DIM + h * HD);
        float4 kv[8];
        #pragma unroll
        for (int q = 0; q < 8; ++q) kv[q] = kp[q];
        for (int r = 0; r < nrows; ++r) {
            const float4* qp = (const float4*)(Q + (size_t)(row0 + r) * DIM + h * HD);
            float d0 = 0.f, d1 = 0.f, d2 = 0.f, d3 = 0.f;
            #pragma unroll
            for (int q = 0; q < 8; ++q) {
                float4 qv = qp[q];                 // uniform address -> s_load
                d0 = fmaf(qv.x, kv[q].x, d0);
                d1 = fmaf(qv.y, kv[q].y, d1);
                d2 = fmaf(qv.z, kv[q].z, d2);
                d3 = fmaf(qv.w, kv[q].w, d3);
            }
            s[r][t] = ((d0 + d1) + (d2 + d3)) * SCALE;
        }
    }
    __syncthreads();

    // ---- edge-bias scatter (duplicates accumulate via LDS atomics)
    {
        int e0 = rs_sh[0], e1 = rs_sh[nrows];
        for (int idx = e0 + t; idx < e1; idx += 256) {
            int lo = 0, hi = nrows;
            while (hi - lo > 1) {
                int mid = (lo + hi) >> 1;
                if (rs_sh[mid] <= idx) lo = mid; else hi = mid;
            }
            int col = ecol[idx] - gs;
            if (col >= 0 && col < ncols)
                atomicAdd(&s[lo][col], ebias[(size_t)h * E_EDGES + idx]);
        }
    }
    __syncthreads();

    // ---- softmax: 16 lanes per row, store unnormalized exp
    {
        int r = t >> 4, sub = t & 15;
        if (r < nrows) {
            float m = -INFINITY;
            for (int c = sub; c < ncols; c += 16) m = fmaxf(m, s[r][c]);
            m = fmaxf(m, __shfl_xor(m, 1, 16));
            m = fmaxf(m, __shfl_xor(m, 2, 16));
            m = fmaxf(m, __shfl_xor(m, 4, 16));
            m = fmaxf(m, __shfl_xor(m, 8, 16));
            float sum = 0.f;
            for (int c = sub; c < ncols; c += 16) {
                float e = __expf(s[r][c] - m);
                s[r][c] = e;
                sum += e;
            }
            sum += __shfl_xor(sum, 1, 16);
            sum += __shfl_xor(sum, 2, 16);
            sum += __shfl_xor(sum, 4, 16);
            sum += __shfl_xor(sum, 8, 16);
            if (sub == 0) rowinv[r] = 1.0f / sum;
        }
    }
    __syncthreads();

    // ---- PV: thread = (row r, k-octet kg, col-phase csub); 8 accumulators
    {
        const int r = t >> 4, kg = (t >> 2) & 3, csub = t & 3;
        float a[8] = {0,0,0,0,0,0,0,0};
        if (r < nrows) {
            const float4* vb = (const float4*)V;
            const size_t vbase = (size_t)gs * (DIM / 4) + h * (HD / 4) + kg * 2;
            for (int c = csub; c < ncols; c += 4) {
                float p = s[r][c];
                float4 v0 = vb[vbase + (size_t)c * (DIM / 4)];
                float4 v1 = vb[vbase + (size_t)c * (DIM / 4) + 1];
                a[0] = fmaf(p, v0.x, a[0]); a[1] = fmaf(p, v0.y, a[1]);
                a[2] = fmaf(p, v0.z, a[2]); a[3] = fmaf(p, v0.w, a[3]);
                a[4] = fmaf(p, v1.x, a[4]); a[5] = fmaf(p, v1.y, a[5]);
                a[6] = fmaf(p, v1.z, a[6]); a[7] = fmaf(p, v1.w, a[7]);
            }
        }
        #pragma unroll
        for (int i = 0; i < 8; ++i) {
            a[i] += __shfl_xor(a[i], 1, 4);
            a[i] += __shfl_xor(a[i], 2, 4);
        }
        if (r < nrows) {
            float sc = rowinv[r];
            float o0 = (csub == 0) ? a[0] : (csub == 1) ? a[2] : (csub == 2) ? a[4] : a[6];
            float o1 = (csub == 0) ? a[1] : (csub == 1) ? a[3] : (csub == 2) ? a[5] : a[7];
            float2* dst = (float2*)&pre[(size_t)(row0 + r) * DIM + h * HD + kg * 8 + csub * 2];
            *dst = make_float2(o0 * sc, o1 * sc);
        }
    }
}

// ---------------- output projection ----------------
// grid 384, block 256: thread = output column, 8 rows/block; pre rows scalar-loaded.
__global__ __launch_bounds__(256) void out_proj(
    const float* __restrict__ pre, const float* __restrict__ Wo,
    const float* __restrict__ bo, float* __restrict__ out)
{
    const int row0 = blockIdx.x * 8;
    const int col  = threadIdx.x;
    float acc[8] = {0,0,0,0,0,0,0,0};
    const float4* xr = (const float4*)(pre + (size_t)row0 * DIM);

    for (int k4 = 0; k4 < DIM / 4; ++k4) {
        float4 xv[8];
        #pragma unroll
        for (int r = 0; r < 8; ++r) xv[r] = xr[(size_t)r * (DIM / 4) + k4];
        const int kb = k4 * 4;
        #define O_STEP(COMP, KK) { \
            float w = Wo[(size_t)(kb + KK) * DIM + col]; \
            _Pragma("unroll") \
            for (int r = 0; r < 8; ++r) acc[r] = fmaf(xv[r].COMP, w, acc[r]); }
        O_STEP(x, 0) O_STEP(y, 1) O_STEP(z, 2) O_STEP(w, 3)
        #undef O_STEP
    }
    float b = bo[col];
    #pragma unroll
    for (int r = 0; r < 8; ++r) out[(size_t)(row0 + r) * DIM + col] = acc[r] + b;
}

// ---------------- launch ----------------
extern "C" void kernel_launch(void* const* d_in, const int* in_sizes, int n_in,
                              void* d_out, int out_size, void* d_ws, size_t ws_size,
                              hipStream_t stream) {
    const float* x   = (const float*)d_in[0];
    const float* ea  = (const float*)d_in[1];
    const float* Wq  = (const float*)d_in[2];  const float* bq = (const float*)d_in[3];
    const float* Wk  = (const float*)d_in[4];  const float* bk = (const float*)d_in[5];
    const float* Wv  = (const float*)d_in[6];  const float* bv = (const float*)d_in[7];
    const float* Wo  = (const float*)d_in[8];  const float* bo = (const float*)d_in[9];
    const float* We  = (const float*)d_in[10]; const float* be = (const float*)d_in[11];
    const int*   eidx  = (const int*)d_in[12];
    const int*   batch = (const int*)d_in[13];
    const int* erow   = eidx;
    const int* ecolin = eidx + E_EDGES;

    // workspace layout
    float* Q   = (float*)d_ws;
    float* K   = Q + (size_t)N_NODES * DIM;
    float* V   = K + (size_t)N_NODES * DIM;
    float* pre = V + (size_t)N_NODES * DIM;
    int* counts   = (int*)(pre + (size_t)N_NODES * DIM);
    int* cursor   = counts + N_NODES;
    int* rowstart = cursor + N_NODES;          // N+1
    int* gstart   = rowstart + (N_NODES + 1);  // B+1
    int* ecol     = gstart + (B_GRAPHS + 1);
    float* ebias  = (float*)(ecol + E_EDGES);  // [NH][E]

    setup_misc<<<dim3((2 * N_NODES + 255) / 256), dim3(256), 0, stream>>>(batch, counts, gstart);
    qkv_proj<<<dim3(N_NODES / 8), dim3(256), 0, stream>>>(x, Wq, bq, Wk, bk, Wv, bv, Q, K, V);
    edge_count<<<dim3(E_EDGES / 256), dim3(256), 0, stream>>>(erow, counts);
    scan_rows<<<dim3(1), dim3(1024), 0, stream>>>(counts, rowstart);
    edge_fill<<<dim3(E_EDGES / 256), dim3(256), 0, stream>>>(erow, ecolin, ea, We, be,
                                                             rowstart, cursor, ecol, ebias);
    attn<<<dim3(B_GRAPHS, 24, NH), dim3(256), 0, stream>>>(Q, K, V, gstart, rowstart,
                                                           ecol, ebias, pre);
    out_proj<<<dim3(N_NODES / 8), dim3(256), 0, stream>>>(pre, Wo, bo, (float*)d_out);
}

// Round 3
// 185.911 us; speedup vs baseline: 1.5307x; 1.5307x over previous
//
#include <hip/hip_runtime.h>
#include <hip/hip_bf16.h>
#include <math.h>

#define N_NODES 3072
#define DIM     256
#define NH      8
#define HD      32
#define E_EDGES 98304
#define B_GRAPHS 16
#define MAXC    390     // fp32 score stride: 390%32=6 -> conflict-free C-layout writes
#define PADP    392     // bf16 P stride: 784B rows, 16B-aligned frag reads
#define TR      16      // rows per attention tile
#define SCALE   0.17677669529663689f   // 1/sqrt(32)

typedef __attribute__((ext_vector_type(8))) short bf16x8;   // 8 bf16 (4 VGPRs)
typedef __attribute__((ext_vector_type(4))) float f32x4;

__device__ inline unsigned short f2b(float f) {
    __hip_bfloat16 h = __float2bfloat16(f);
    return *reinterpret_cast<unsigned short*>(&h);
}

// ---------------- setup: zero counters + graph ranges ----------------
__global__ void setup_misc(const int* __restrict__ batch, int* __restrict__ counts,
                           int* __restrict__ gstart) {
    int i = blockIdx.x * blockDim.x + threadIdx.x;
    if (i < 2 * N_NODES) counts[i] = 0;
    if (i < N_NODES) {
        int b  = batch[i];
        int bp = (i == 0) ? -1 : batch[i - 1];
        for (int g = bp + 1; g <= b; ++g) gstart[g] = i;
        if (i == N_NODES - 1)
            for (int g = b + 1; g <= B_GRAPHS; ++g) gstart[g] = N_NODES;
    }
}

// ---------------- fused QKV projection (round-1 structure, bf16 out) ----------------
__global__ __launch_bounds__(256) void qkv_proj(
    const float* __restrict__ x,
    const float* __restrict__ Wq, const float* __restrict__ bq,
    const float* __restrict__ Wk, const float* __restrict__ bk,
    const float* __restrict__ Wv, const float* __restrict__ bv,
    unsigned short* __restrict__ Qb, unsigned short* __restrict__ Kb,
    unsigned short* __restrict__ Vb)
{
    __shared__ float xs[8][DIM];
    const int row0 = blockIdx.x * 8;
    const int t = threadIdx.x;
    for (int i = t; i < 8 * DIM; i += 256) xs[i >> 8][i & 255] = x[(size_t)row0 * DIM + i];
    __syncthreads();

    float accQ[8] = {0,0,0,0,0,0,0,0};
    float accK[8] = {0,0,0,0,0,0,0,0};
    float accV[8] = {0,0,0,0,0,0,0,0};
    const int j = t;
    #pragma unroll 4
    for (int k = 0; k < DIM; ++k) {
        float wq = Wq[k * DIM + j];
        float wk = Wk[k * DIM + j];
        float wv = Wv[k * DIM + j];
        #pragma unroll
        for (int r = 0; r < 8; ++r) {
            float xv = xs[r][k];
            accQ[r] = fmaf(xv, wq, accQ[r]);
            accK[r] = fmaf(xv, wk, accK[r]);
            accV[r] = fmaf(xv, wv, accV[r]);
        }
    }
    float bqv = bq[j], bkv = bk[j], bvv = bv[j];
    #pragma unroll
    for (int r = 0; r < 8; ++r) {
        size_t o = (size_t)(row0 + r) * DIM + j;
        Qb[o] = f2b(accQ[r] + bqv);
        Kb[o] = f2b(accK[r] + bkv);
        Vb[o] = f2b(accV[r] + bvv);
    }
}

// ---------------- edge CSR build ----------------
__global__ void edge_count(const int* __restrict__ erow, int* __restrict__ counts) {
    int e = blockIdx.x * blockDim.x + threadIdx.x;
    if (e < E_EDGES) atomicAdd(&counts[erow[e]], 1);
}

__global__ __launch_bounds__(1024) void scan_rows(const int* __restrict__ counts,
                                                  int* __restrict__ rowstart) {
    __shared__ int lds[1024];
    const int t = threadIdx.x;
    int c0 = counts[3 * t], c1 = counts[3 * t + 1], c2 = counts[3 * t + 2];
    int local = c0 + c1 + c2;
    lds[t] = local;
    __syncthreads();
    for (int off = 1; off < 1024; off <<= 1) {
        int v = (t >= off) ? lds[t - off] : 0;
        __syncthreads();
        lds[t] += v;
        __syncthreads();
    }
    int incl = lds[t];
    int base = incl - local;
    rowstart[3 * t]     = base;
    rowstart[3 * t + 1] = base + c0;
    rowstart[3 * t + 2] = base + c0 + c1;
    if (t == 1023) rowstart[N_NODES] = incl;
}

__global__ void edge_fill(const int* __restrict__ erow, const int* __restrict__ ecolin,
                          const float* __restrict__ ea, const float* __restrict__ We,
                          const float* __restrict__ be,
                          const int* __restrict__ rowstart, int* __restrict__ cursor,
                          int* __restrict__ ecol, float* __restrict__ ebias) {
    int e = blockIdx.x * blockDim.x + threadIdx.x;
    if (e >= E_EDGES) return;
    int row = erow[e];
    int pos = rowstart[row] + atomicAdd(&cursor[row], 1);
    ecol[pos] = ecolin[e];
    float a0 = ea[e * 4 + 0], a1 = ea[e * 4 + 1], a2 = ea[e * 4 + 2], a3 = ea[e * 4 + 3];
    #pragma unroll
    for (int h = 0; h < NH; ++h) {
        float b = fmaf(a0, We[0 * NH + h],
                  fmaf(a1, We[1 * NH + h],
                  fmaf(a2, We[2 * NH + h],
                  fmaf(a3, We[3 * NH + h], be[h]))));
        ebias[(size_t)h * E_EDGES + pos] = b;   // [h][E]
    }
}

// ---------------- MFMA block-diagonal attention ----------------
// grid (16 graphs, 24 tiles, 8 heads), block 256 (4 waves), TR=16 rows/tile
__global__ __launch_bounds__(256) void attn(
    const unsigned short* __restrict__ Qb, const unsigned short* __restrict__ Kb,
    const unsigned short* __restrict__ Vb,
    const int* __restrict__ gstart, const int* __restrict__ rowstart,
    const int* __restrict__ ecol, const float* __restrict__ ebias,
    float* __restrict__ pre)
{
    __shared__ float s[TR][MAXC];                 // scores fp32; reused as PV reduce buf
    __shared__ unsigned short pb[TR][PADP];       // probabilities bf16 (A-frag layout)
    __shared__ float rowinv[TR];
    __shared__ int   rs_sh[TR + 1];

    const int g = blockIdx.x, tile = blockIdx.y, h = blockIdx.z;
    const int gs = gstart[g], ge = gstart[g + 1];
    const int row0 = gs + tile * TR;
    if (row0 >= ge) return;
    const int nrows = min(TR, ge - row0);
    const int ncols = ge - gs;
    const int cpad  = (ncols + 31) & ~31;
    const int t = threadIdx.x;
    const int wave = t >> 6, lane = t & 63;
    const int l16 = lane & 15, lq = lane >> 4;    // frag col / quad

    if (t <= nrows) rs_sh[t] = rowstart[row0 + t];

    // ---- QK^T via MFMA: A = Q row-tile (held per-wave), B = K chunk
    {
        int arow = min(row0 + l16, N_NODES - 1);
        const bf16x8 aq = *(const bf16x8*)(Qb + (size_t)arow * DIM + h * HD + (lq << 3));
        const int nchunk16 = (ncols + 15) >> 4;
        for (int j = wave; j < nchunk16; j += 4) {
            const int c0 = j << 4;
            int krow = min(gs + c0 + l16, N_NODES - 1);
            bf16x8 bk = *(const bf16x8*)(Kb + (size_t)krow * DIM + h * HD + (lq << 3));
            f32x4 d = {0.f, 0.f, 0.f, 0.f};
            d = __builtin_amdgcn_mfma_f32_16x16x32_bf16(aq, bk, d, 0, 0, 0);
            const int col = c0 + l16, rbase = lq * 4;
            #pragma unroll
            for (int r = 0; r < 4; ++r) s[rbase + r][col] = d[r] * SCALE;
        }
    }
    __syncthreads();

    // ---- edge-bias scatter (duplicates accumulate via LDS atomics)
    {
        int e0 = rs_sh[0], e1 = rs_sh[nrows];
        for (int idx = e0 + t; idx < e1; idx += 256) {
            int lo = 0, hi = nrows;
            while (hi - lo > 1) {
                int mid = (lo + hi) >> 1;
                if (rs_sh[mid] <= idx) lo = mid; else hi = mid;
            }
            int col = ecol[idx] - gs;
            if (col >= 0 && col < ncols)
                atomicAdd(&s[lo][col], ebias[(size_t)h * E_EDGES + idx]);
        }
    }
    __syncthreads();

    // ---- softmax: 16 lanes/row; emit bf16 P (zero-padded to chunk boundary)
    {
        const int r = t >> 4, sub = t & 15;
        if (r < nrows) {
            float m = -INFINITY;
            for (int c = sub; c < ncols; c += 16) m = fmaxf(m, s[r][c]);
            m = fmaxf(m, __shfl_xor(m, 1, 16));
            m = fmaxf(m, __shfl_xor(m, 2, 16));
            m = fmaxf(m, __shfl_xor(m, 4, 16));
            m = fmaxf(m, __shfl_xor(m, 8, 16));
            float sum = 0.f;
            for (int c = sub; c < cpad; c += 16) {
                if (c < ncols) {
                    float e = __expf(s[r][c] - m);
                    sum += e;
                    pb[r][c] = f2b(e);
                } else {
                    pb[r][c] = 0;
                }
            }
            sum += __shfl_xor(sum, 1, 16);
            sum += __shfl_xor(sum, 2, 16);
            sum += __shfl_xor(sum, 4, 16);
            sum += __shfl_xor(sum, 8, 16);
            if (sub == 0) rowinv[r] = 1.0f / sum;
        } else {
            for (int c = sub; c < cpad; c += 16) pb[r][c] = 0;  // dead rows -> P=0
        }
    }
    __syncthreads();

    // ---- PV via MFMA: waves split (kout-half, chunk-parity); partials in regs
    f32x4 o = {0.f, 0.f, 0.f, 0.f};
    {
        const int half = wave >> 1, par = wave & 1;
        const int kout = l16 + (half << 4);
        const int nchunk32 = cpad >> 5;
        for (int j = par; j < nchunk32; j += 2) {
            const int c0 = j << 5;
            bf16x8 ap = *(const bf16x8*)(&pb[l16][c0 + (lq << 3)]);
            bf16x8 bv;
            const int cb = c0 + (lq << 3);
            #pragma unroll
            for (int jj = 0; jj < 8; ++jj) {
                int vr = min(gs + cb + jj, N_NODES - 1);
                bv[jj] = (short)Vb[(size_t)vr * DIM + h * HD + kout];
            }
            o = __builtin_amdgcn_mfma_f32_16x16x32_bf16(ap, bv, o, 0, 0, 0);
        }
    }
    __syncthreads();                 // softmax done reading s -> safe to reuse as reduce buf
    {
        float* red = &s[0][0];       // [4 waves][16 rows][16 kout], stride 17
        const int rbase = lq * 4;
        #pragma unroll
        for (int r = 0; r < 4; ++r)
            red[((wave << 4) + rbase + r) * 17 + l16] = o[r];
    }
    __syncthreads();
    {
        const int row = t >> 4, kl = t & 15;
        if (row < nrows) {
            float* red = &s[0][0];
            float v0 = red[(row) * 17 + kl]        + red[(16 + row) * 17 + kl];
            float v1 = red[(32 + row) * 17 + kl]   + red[(48 + row) * 17 + kl];
            float sc = rowinv[row];
            size_t ob = (size_t)(row0 + row) * DIM + h * HD;
            pre[ob + kl]      = v0 * sc;
            pre[ob + 16 + kl] = v1 * sc;
        }
    }
}

// ---------------- output projection (round-1 structure) ----------------
__global__ __launch_bounds__(256) void out_proj(
    const float* __restrict__ pre, const float* __restrict__ Wo,
    const float* __restrict__ bo, float* __restrict__ out)
{
    __shared__ float xs[8][DIM];
    const int row0 = blockIdx.x * 8;
    const int t = threadIdx.x;
    for (int i = t; i < 8 * DIM; i += 256) xs[i >> 8][i & 255] = pre[(size_t)row0 * DIM + i];
    __syncthreads();

    float acc[8] = {0,0,0,0,0,0,0,0};
    #pragma unroll 4
    for (int k = 0; k < DIM; ++k) {
        float w = Wo[k * DIM + t];
        #pragma unroll
        for (int r = 0; r < 8; ++r) acc[r] = fmaf(xs[r][k], w, acc[r]);
    }
    float b = bo[t];
    #pragma unroll
    for (int r = 0; r < 8; ++r) out[(size_t)(row0 + r) * DIM + t] = acc[r] + b;
}

// ---------------- launch ----------------
extern "C" void kernel_launch(void* const* d_in, const int* in_sizes, int n_in,
                              void* d_out, int out_size, void* d_ws, size_t ws_size,
                              hipStream_t stream) {
    const float* x   = (const float*)d_in[0];
    const float* ea  = (const float*)d_in[1];
    const float* Wq  = (const float*)d_in[2];  const float* bq = (const float*)d_in[3];
    const float* Wk  = (const float*)d_in[4];  const float* bk = (const float*)d_in[5];
    const float* Wv  = (const float*)d_in[6];  const float* bv = (const float*)d_in[7];
    const float* Wo  = (const float*)d_in[8];  const float* bo = (const float*)d_in[9];
    const float* We  = (const float*)d_in[10]; const float* be = (const float*)d_in[11];
    const int*   eidx  = (const int*)d_in[12];
    const int*   batch = (const int*)d_in[13];
    const int* erow   = eidx;
    const int* ecolin = eidx + E_EDGES;

    // workspace layout
    unsigned short* Qb = (unsigned short*)d_ws;            // N*D bf16
    unsigned short* Kb = Qb + (size_t)N_NODES * DIM;
    unsigned short* Vb = Kb + (size_t)N_NODES * DIM;
    float* pre = (float*)(Vb + (size_t)N_NODES * DIM);     // N*D fp32
    int* counts   = (int*)(pre + (size_t)N_NODES * DIM);
    int* cursor   = counts + N_NODES;
    int* rowstart = cursor + N_NODES;          // N+1
    int* gstart   = rowstart + (N_NODES + 1);  // B+1
    int* ecol     = gstart + (B_GRAPHS + 1);
    float* ebias  = (float*)(ecol + E_EDGES);  // [NH][E]

    setup_misc<<<dim3((2 * N_NODES + 255) / 256), dim3(256), 0, stream>>>(batch, counts, gstart);
    qkv_proj<<<dim3(N_NODES / 8), dim3(256), 0, stream>>>(x, Wq, bq, Wk, bk, Wv, bv, Qb, Kb, Vb);
    edge_count<<<dim3(E_EDGES / 256), dim3(256), 0, stream>>>(erow, counts);
    scan_rows<<<dim3(1), dim3(1024), 0, stream>>>(counts, rowstart);
    edge_fill<<<dim3(E_EDGES / 256), dim3(256), 0, stream>>>(erow, ecolin, ea, We, be,
                                                             rowstart, cursor, ecol, ebias);
    attn<<<dim3(B_GRAPHS, 24, NH), dim3(256), 0, stream>>>(Qb, Kb, Vb, gstart, rowstart,
                                                           ecol, ebias, pre);
    out_proj<<<dim3(N_NODES / 8), dim3(256), 0, stream>>>(pre, Wo, bo, (float*)d_out);
}

// Round 4
// 175.722 us; speedup vs baseline: 1.6194x; 1.0580x over previous
//
#include <hip/hip_runtime.h>
#include <hip/hip_bf16.h>
#include <math.h>

#define N_NODES 3072
#define DIM     256
#define NH      8
#define HD      32
#define E_EDGES 98304
#define B_GRAPHS 16
#define MAXC    390     // fp32 score stride: 390%32=6 -> conflict-free C-layout writes
#define PADP    392     // bf16 P stride: 784B rows, 16B-aligned frag reads
#define TR      16      // rows per attention tile
#define SCALE   0.17677669529663689f   // 1/sqrt(32)

typedef __attribute__((ext_vector_type(8))) short bf16x8;   // 8 bf16 (4 VGPRs)
typedef __attribute__((ext_vector_type(4))) float f32x4;
typedef __attribute__((ext_vector_type(4))) unsigned short ushort4v;

__device__ inline unsigned short f2b(float f) {
    __hip_bfloat16 h = __float2bfloat16(f);
    return *reinterpret_cast<unsigned short*>(&h);
}
__device__ inline float b2f(unsigned short u) {
    __hip_bfloat16 h = *reinterpret_cast<__hip_bfloat16*>(&u);
    return __bfloat162float(h);
}

// ---------------- prep: x hi/lo split + W transpose hi/lo + counters + gstart ----
// grid 1048: [0,768) x-split, [768,1024) W-transpose, [1024,1048) counters/gstart
__global__ __launch_bounds__(256) void prep(
    const float* __restrict__ x,
    const float* __restrict__ Wq, const float* __restrict__ Wk,
    const float* __restrict__ Wv, const float* __restrict__ Wo,
    unsigned short* __restrict__ xh, unsigned short* __restrict__ xl,
    unsigned short* __restrict__ Wth, unsigned short* __restrict__ Wtl,
    const int* __restrict__ batch, int* __restrict__ counts, int* __restrict__ gstart)
{
    const int b = blockIdx.x, t = threadIdx.x;
    if (b < 768) {                       // ---- x split, float4 granularity
        const int gid = b * 256 + t;     // 196608 float4's
        float4 v = ((const float4*)x)[gid];
        ushort4v h, l;
        float c[4] = {v.x, v.y, v.z, v.w};
        #pragma unroll
        for (int i = 0; i < 4; ++i) {
            unsigned short hi = f2b(c[i]);
            h[i] = hi;
            l[i] = f2b(c[i] - b2f(hi));
        }
        ((ushort4v*)xh)[gid] = h;
        ((ushort4v*)xl)[gid] = l;
    } else if (b < 1024) {               // ---- W transpose 32x32 tiles
        __shared__ float tile[32][33];
        const int wb = b - 768;
        const int mat = wb >> 6, tidx = wb & 63;
        const int tk = (tidx >> 3) * 32, tn = (tidx & 7) * 32;
        const float* W = (mat == 0) ? Wq : (mat == 1) ? Wk : (mat == 2) ? Wv : Wo;
        const int kk = t >> 5, nn = t & 31;
        #pragma unroll
        for (int p = 0; p < 4; ++p)
            tile[nn][kk + p * 8] = W[(size_t)(tk + kk + p * 8) * DIM + tn + nn];
        __syncthreads();
        const int n = t >> 3, kq = (t & 7) * 4;
        ushort4v h, l;
        #pragma unroll
        for (int i = 0; i < 4; ++i) {
            float v = tile[n][kq + i];
            unsigned short hi = f2b(v);
            h[i] = hi;
            l[i] = f2b(v - b2f(hi));
        }
        size_t o = (size_t)mat * DIM * DIM + (size_t)(tn + n) * DIM + tk + kq;
        *(ushort4v*)(Wth + o) = h;
        *(ushort4v*)(Wtl + o) = l;
    } else {                             // ---- counters + graph ranges
        const int i = (b - 1024) * 256 + t;
        if (i < 2 * N_NODES) counts[i] = 0;
        if (i < N_NODES) {
            int bb = batch[i];
            int bp = (i == 0) ? -1 : batch[i - 1];
            for (int g = bp + 1; g <= bb; ++g) gstart[g] = i;
            if (i == N_NODES - 1)
                for (int g = bb + 1; g <= B_GRAPHS; ++g) gstart[g] = N_NODES;
        }
    }
}

// ---------------- QKV projection via split-bf16 MFMA ----------------
// grid (96, 6), block 256 = 4 waves; wave tile 16 rows x 64 cols; block 32 x 128.
// blockIdx.y: 0-1 -> Q, 2-3 -> K, 4-5 -> V. Barrier-free; frags from global (L2-hot).
__global__ __launch_bounds__(256) void qkv_mfma(
    const unsigned short* __restrict__ xh, const unsigned short* __restrict__ xl,
    const unsigned short* __restrict__ Wth, const unsigned short* __restrict__ Wtl,
    const float* __restrict__ bq, const float* __restrict__ bk, const float* __restrict__ bv,
    unsigned short* __restrict__ Qb, unsigned short* __restrict__ Kb,
    unsigned short* __restrict__ Vb)
{
    const int t = threadIdx.x, w = t >> 6, lane = t & 63;
    const int l16 = lane & 15, lq = lane >> 4;
    const int mat = blockIdx.y >> 1;
    const int rb = blockIdx.x * 32 + (w & 1) * 16;
    const int nb = (blockIdx.y & 1) * 128 + (w >> 1) * 64;   // col base within matrix
    const unsigned short* Wh = Wth + (size_t)mat * DIM * DIM;
    const unsigned short* Wl = Wtl + (size_t)mat * DIM * DIM;

    f32x4 acc[4] = {{0,0,0,0},{0,0,0,0},{0,0,0,0},{0,0,0,0}};
    const size_t arow = (size_t)(rb + l16) * DIM + (lq << 3);

    #pragma unroll
    for (int kc = 0; kc < 8; ++kc) {
        const int k = kc * 32;
        bf16x8 ah = *(const bf16x8*)(xh + arow + k);
        bf16x8 al = *(const bf16x8*)(xl + arow + k);
        #pragma unroll
        for (int ct = 0; ct < 4; ++ct) {
            const size_t bo_ = (size_t)(nb + ct * 16 + l16) * DIM + k + (lq << 3);
            bf16x8 bh = *(const bf16x8*)(Wh + bo_);
            bf16x8 bl = *(const bf16x8*)(Wl + bo_);
            acc[ct] = __builtin_amdgcn_mfma_f32_16x16x32_bf16(ah, bh, acc[ct], 0, 0, 0);
            acc[ct] = __builtin_amdgcn_mfma_f32_16x16x32_bf16(ah, bl, acc[ct], 0, 0, 0);
            acc[ct] = __builtin_amdgcn_mfma_f32_16x16x32_bf16(al, bh, acc[ct], 0, 0, 0);
        }
    }

    const float* bias = (mat == 0) ? bq : (mat == 1) ? bk : bv;
    unsigned short* outp = (mat == 0) ? Qb : (mat == 1) ? Kb : Vb;
    #pragma unroll
    for (int ct = 0; ct < 4; ++ct) {
        const int n = nb + ct * 16 + l16;
        const float bvl = bias[n];
        #pragma unroll
        for (int r = 0; r < 4; ++r) {
            const int row = rb + lq * 4 + r;
            outp[(size_t)row * DIM + n] = f2b(acc[ct][r] + bvl);
        }
    }
}

// ---------------- edge CSR build ----------------
__global__ void edge_count(const int* __restrict__ erow, int* __restrict__ counts) {
    int e = blockIdx.x * blockDim.x + threadIdx.x;
    if (e < E_EDGES) atomicAdd(&counts[erow[e]], 1);
}

__global__ __launch_bounds__(1024) void scan_rows(const int* __restrict__ counts,
                                                  int* __restrict__ rowstart) {
    __shared__ int lds[1024];
    const int t = threadIdx.x;
    int c0 = counts[3 * t], c1 = counts[3 * t + 1], c2 = counts[3 * t + 2];
    int local = c0 + c1 + c2;
    lds[t] = local;
    __syncthreads();
    for (int off = 1; off < 1024; off <<= 1) {
        int v = (t >= off) ? lds[t - off] : 0;
        __syncthreads();
        lds[t] += v;
        __syncthreads();
    }
    int incl = lds[t];
    int base = incl - local;
    rowstart[3 * t]     = base;
    rowstart[3 * t + 1] = base + c0;
    rowstart[3 * t + 2] = base + c0 + c1;
    if (t == 1023) rowstart[N_NODES] = incl;
}

__global__ void edge_fill(const int* __restrict__ erow, const int* __restrict__ ecolin,
                          const float* __restrict__ ea, const float* __restrict__ We,
                          const float* __restrict__ be,
                          const int* __restrict__ rowstart, int* __restrict__ cursor,
                          int* __restrict__ ecol, float* __restrict__ ebias) {
    int e = blockIdx.x * blockDim.x + threadIdx.x;
    if (e >= E_EDGES) return;
    int row = erow[e];
    int pos = rowstart[row] + atomicAdd(&cursor[row], 1);
    ecol[pos] = ecolin[e];
    float a0 = ea[e * 4 + 0], a1 = ea[e * 4 + 1], a2 = ea[e * 4 + 2], a3 = ea[e * 4 + 3];
    #pragma unroll
    for (int h = 0; h < NH; ++h) {
        float b = fmaf(a0, We[0 * NH + h],
                  fmaf(a1, We[1 * NH + h],
                  fmaf(a2, We[2 * NH + h],
                  fmaf(a3, We[3 * NH + h], be[h]))));
        ebias[(size_t)h * E_EDGES + pos] = b;   // [h][E]
    }
}

// ---------------- MFMA block-diagonal attention ----------------
// grid (16 graphs, 24 tiles, 8 heads), block 256 (4 waves), TR=16 rows/tile
__global__ __launch_bounds__(256) void attn(
    const unsigned short* __restrict__ Qb, const unsigned short* __restrict__ Kb,
    const unsigned short* __restrict__ Vb,
    const int* __restrict__ gstart, const int* __restrict__ rowstart,
    const int* __restrict__ ecol, const float* __restrict__ ebias,
    unsigned short* __restrict__ preh, unsigned short* __restrict__ prel)
{
    __shared__ float s[TR][MAXC];                 // scores fp32; reused as PV reduce buf
    __shared__ unsigned short pb[TR][PADP];       // probabilities bf16 (A-frag layout)
    __shared__ float rowinv[TR];
    __shared__ int   rs_sh[TR + 1];

    const int g = blockIdx.x, tile = blockIdx.y, h = blockIdx.z;
    const int gs = gstart[g], ge = gstart[g + 1];
    const int row0 = gs + tile * TR;
    if (row0 >= ge) return;
    const int nrows = min(TR, ge - row0);
    const int ncols = ge - gs;
    const int cpad  = (ncols + 31) & ~31;
    const int t = threadIdx.x;
    const int wave = t >> 6, lane = t & 63;
    const int l16 = lane & 15, lq = lane >> 4;

    if (t <= nrows) rs_sh[t] = rowstart[row0 + t];

    // ---- QK^T via MFMA
    {
        int arow = min(row0 + l16, N_NODES - 1);
        const bf16x8 aq = *(const bf16x8*)(Qb + (size_t)arow * DIM + h * HD + (lq << 3));
        const int nchunk16 = (ncols + 15) >> 4;
        for (int j = wave; j < nchunk16; j += 4) {
            const int c0 = j << 4;
            int krow = min(gs + c0 + l16, N_NODES - 1);
            bf16x8 bk = *(const bf16x8*)(Kb + (size_t)krow * DIM + h * HD + (lq << 3));
            f32x4 d = {0.f, 0.f, 0.f, 0.f};
            d = __builtin_amdgcn_mfma_f32_16x16x32_bf16(aq, bk, d, 0, 0, 0);
            const int col = c0 + l16, rbase = lq * 4;
            #pragma unroll
            for (int r = 0; r < 4; ++r) s[rbase + r][col] = d[r] * SCALE;
        }
    }
    __syncthreads();

    // ---- edge-bias scatter
    {
        int e0 = rs_sh[0], e1 = rs_sh[nrows];
        for (int idx = e0 + t; idx < e1; idx += 256) {
            int lo = 0, hi = nrows;
            while (hi - lo > 1) {
                int mid = (lo + hi) >> 1;
                if (rs_sh[mid] <= idx) lo = mid; else hi = mid;
            }
            int col = ecol[idx] - gs;
            if (col >= 0 && col < ncols)
                atomicAdd(&s[lo][col], ebias[(size_t)h * E_EDGES + idx]);
        }
    }
    __syncthreads();

    // ---- softmax: emit bf16 P, zero-padded
    {
        const int r = t >> 4, sub = t & 15;
        if (r < nrows) {
            float m = -INFINITY;
            for (int c = sub; c < ncols; c += 16) m = fmaxf(m, s[r][c]);
            m = fmaxf(m, __shfl_xor(m, 1, 16));
            m = fmaxf(m, __shfl_xor(m, 2, 16));
            m = fmaxf(m, __shfl_xor(m, 4, 16));
            m = fmaxf(m, __shfl_xor(m, 8, 16));
            float sum = 0.f;
            for (int c = sub; c < cpad; c += 16) {
                if (c < ncols) {
                    float e = __expf(s[r][c] - m);
                    sum += e;
                    pb[r][c] = f2b(e);
                } else {
                    pb[r][c] = 0;
                }
            }
            sum += __shfl_xor(sum, 1, 16);
            sum += __shfl_xor(sum, 2, 16);
            sum += __shfl_xor(sum, 4, 16);
            sum += __shfl_xor(sum, 8, 16);
            if (sub == 0) rowinv[r] = 1.0f / sum;
        } else {
            for (int c = sub; c < cpad; c += 16) pb[r][c] = 0;
        }
    }
    __syncthreads();

    // ---- PV via MFMA
    f32x4 o = {0.f, 0.f, 0.f, 0.f};
    {
        const int half = wave >> 1, par = wave & 1;
        const int kout = l16 + (half << 4);
        const int nchunk32 = cpad >> 5;
        for (int j = par; j < nchunk32; j += 2) {
            const int c0 = j << 5;
            bf16x8 ap = *(const bf16x8*)(&pb[l16][c0 + (lq << 3)]);
            bf16x8 bv;
            const int cb = c0 + (lq << 3);
            #pragma unroll
            for (int jj = 0; jj < 8; ++jj) {
                int vr = min(gs + cb + jj, N_NODES - 1);
                bv[jj] = (short)Vb[(size_t)vr * DIM + h * HD + kout];
            }
            o = __builtin_amdgcn_mfma_f32_16x16x32_bf16(ap, bv, o, 0, 0, 0);
        }
    }
    __syncthreads();
    {
        float* red = &s[0][0];       // [4 waves][16 rows][16 kout], stride 17
        const int rbase = lq * 4;
        #pragma unroll
        for (int r = 0; r < 4; ++r)
            red[((wave << 4) + rbase + r) * 17 + l16] = o[r];
    }
    __syncthreads();
    {
        const int row = t >> 4, kl = t & 15;
        if (row < nrows) {
            float* red = &s[0][0];
            float v0 = red[(row) * 17 + kl]        + red[(16 + row) * 17 + kl];
            float v1 = red[(32 + row) * 17 + kl]   + red[(48 + row) * 17 + kl];
            float sc = rowinv[row];
            size_t ob = (size_t)(row0 + row) * DIM + h * HD;
            float f0 = v0 * sc, f1 = v1 * sc;
            unsigned short h0 = f2b(f0), h1 = f2b(f1);
            preh[ob + kl]      = h0;
            preh[ob + 16 + kl] = h1;
            prel[ob + kl]      = f2b(f0 - b2f(h0));
            prel[ob + 16 + kl] = f2b(f1 - b2f(h1));
        }
    }
}

// ---------------- output projection via split-bf16 MFMA ----------------
// grid (192, 2), block 256 = 4 waves; wave tile 16 rows x 32 cols; block 16 x 128.
__global__ __launch_bounds__(256) void out_mfma(
    const unsigned short* __restrict__ preh, const unsigned short* __restrict__ prel,
    const unsigned short* __restrict__ Wth, const unsigned short* __restrict__ Wtl,
    const float* __restrict__ bo, float* __restrict__ out)
{
    const int t = threadIdx.x, w = t >> 6, lane = t & 63;
    const int l16 = lane & 15, lq = lane >> 4;
    const int rb = blockIdx.x * 16;
    const int nb = blockIdx.y * 128 + w * 32;
    const unsigned short* Wh = Wth + (size_t)3 * DIM * DIM;   // Wo^T
    const unsigned short* Wl = Wtl + (size_t)3 * DIM * DIM;

    f32x4 acc[2] = {{0,0,0,0},{0,0,0,0}};
    const size_t arow = (size_t)(rb + l16) * DIM + (lq << 3);

    #pragma unroll
    for (int kc = 0; kc < 8; ++kc) {
        const int k = kc * 32;
        bf16x8 ah = *(const bf16x8*)(preh + arow + k);
        bf16x8 al = *(const bf16x8*)(prel + arow + k);
        #pragma unroll
        for (int ct = 0; ct < 2; ++ct) {
            const size_t bo_ = (size_t)(nb + ct * 16 + l16) * DIM + k + (lq << 3);
            bf16x8 bh = *(const bf16x8*)(Wh + bo_);
            bf16x8 bl = *(const bf16x8*)(Wl + bo_);
            acc[ct] = __builtin_amdgcn_mfma_f32_16x16x32_bf16(ah, bh, acc[ct], 0, 0, 0);
            acc[ct] = __builtin_amdgcn_mfma_f32_16x16x32_bf16(ah, bl, acc[ct], 0, 0, 0);
            acc[ct] = __builtin_amdgcn_mfma_f32_16x16x32_bf16(al, bh, acc[ct], 0, 0, 0);
        }
    }

    #pragma unroll
    for (int ct = 0; ct < 2; ++ct) {
        const int n = nb + ct * 16 + l16;
        const float bvl = bo[n];
        #pragma unroll
        for (int r = 0; r < 4; ++r) {
            const int row = rb + lq * 4 + r;
            out[(size_t)row * DIM + n] = acc[ct][r] + bvl;
        }
    }
}

// ---------------- launch ----------------
extern "C" void kernel_launch(void* const* d_in, const int* in_sizes, int n_in,
                              void* d_out, int out_size, void* d_ws, size_t ws_size,
                              hipStream_t stream) {
    const float* x   = (const float*)d_in[0];
    const float* ea  = (const float*)d_in[1];
    const float* Wq  = (const float*)d_in[2];  const float* bq = (const float*)d_in[3];
    const float* Wk  = (const float*)d_in[4];  const float* bk = (const float*)d_in[5];
    const float* Wv  = (const float*)d_in[6];  const float* bv = (const float*)d_in[7];
    const float* Wo  = (const float*)d_in[8];  const float* bo = (const float*)d_in[9];
    const float* We  = (const float*)d_in[10]; const float* be = (const float*)d_in[11];
    const int*   eidx  = (const int*)d_in[12];
    const int*   batch = (const int*)d_in[13];
    const int* erow   = eidx;
    const int* ecolin = eidx + E_EDGES;

    const size_t ND = (size_t)N_NODES * DIM;     // 786432
    const size_t WD = (size_t)DIM * DIM;         // 65536

    unsigned short* Qb   = (unsigned short*)d_ws;
    unsigned short* Kb   = Qb + ND;
    unsigned short* Vb   = Kb + ND;
    unsigned short* preh = Vb + ND;
    unsigned short* prel = preh + ND;
    unsigned short* xh   = prel + ND;
    unsigned short* xl   = xh + ND;
    unsigned short* Wth  = xl + ND;              // 4 * 65536
    unsigned short* Wtl  = Wth + 4 * WD;
    int* counts   = (int*)(Wtl + 4 * WD);
    int* cursor   = counts + N_NODES;
    int* rowstart = cursor + N_NODES;            // N+1
    int* gstart   = rowstart + (N_NODES + 1);    // B+1
    int* ecol     = gstart + (B_GRAPHS + 1);
    float* ebias  = (float*)(ecol + E_EDGES);    // [NH][E]

    prep<<<dim3(1048), dim3(256), 0, stream>>>(x, Wq, Wk, Wv, Wo, xh, xl, Wth, Wtl,
                                               batch, counts, gstart);
    qkv_mfma<<<dim3(96, 6), dim3(256), 0, stream>>>(xh, xl, Wth, Wtl, bq, bk, bv,
                                                    Qb, Kb, Vb);
    edge_count<<<dim3(E_EDGES / 256), dim3(256), 0, stream>>>(erow, counts);
    scan_rows<<<dim3(1), dim3(1024), 0, stream>>>(counts, rowstart);
    edge_fill<<<dim3(E_EDGES / 256), dim3(256), 0, stream>>>(erow, ecolin, ea, We, be,
                                                             rowstart, cursor, ecol, ebias);
    attn<<<dim3(B_GRAPHS, 24, NH), dim3(256), 0, stream>>>(Qb, Kb, Vb, gstart, rowstart,
                                                           ecol, ebias, preh, prel);
    out_mfma<<<dim3(192, 2), dim3(256), 0, stream>>>(preh, prel, Wth, Wtl, bo, (float*)d_out);
}